// Round 1
// baseline (319.146 us; speedup 1.0000x reference)
//
#include <hip/hip_runtime.h>

typedef unsigned short u16;
typedef __attribute__((ext_vector_type(8))) short bf16x8;
typedef __attribute__((ext_vector_type(4))) float f32x4;
typedef __attribute__((ext_vector_type(8))) unsigned short ushort8;

#define SQ 4096
#define HQ 128

__device__ __forceinline__ u16 f2b(float f) {
  unsigned int u = __float_as_uint(f);
  unsigned int r = (u + 0x7fffu + ((u >> 16) & 1u)) >> 16;  // RNE bf16
  return (u16)r;
}

// x f32 -> bf16, 8 elems/thread
__global__ __launch_bounds__(256) void k_convx(const float* __restrict__ x, u16* __restrict__ xb) {
  long i = (long)(blockIdx.x * 256 + threadIdx.x) * 8;
  float4 a = *(const float4*)(x + i);
  float4 c = *(const float4*)(x + i + 4);
  ushort8 o;
  o[0]=f2b(a.x); o[1]=f2b(a.y); o[2]=f2b(a.z); o[3]=f2b(a.w);
  o[4]=f2b(c.x); o[5]=f2b(c.y); o[6]=f2b(c.z); o[7]=f2b(c.w);
  *(ushort8*)(xb + i) = o;
}

// Wt[z][n][k] = W_z[k][n]  (bf16, B^T layout for MFMA B-frags)
__global__ __launch_bounds__(256) void k_wt(const float* __restrict__ Wq, const float* __restrict__ Wk,
                                            const float* __restrict__ Wv, u16* __restrict__ wt) {
  int idx = blockIdx.x * 256 + threadIdx.x;
  int z = idx >> 17, r = idx & 131071, n = r >> 10, k = r & 1023;
  const float* W = (z == 0) ? Wq : (z == 1) ? Wk : Wv;
  wt[idx] = f2b(W[k * 128 + n]);
}

// C = xb @ Wz^T(stored as Wt[n][k]); 128x128 tile, 4 waves 2x2, 16x16x32 bf16
__global__ __launch_bounds__(256) void k_proj(const u16* __restrict__ xb, const u16* __restrict__ wt,
                                              u16* __restrict__ qb, u16* __restrict__ kb,
                                              u16* __restrict__ vt) {
  int mt = blockIdx.x, z = blockIdx.y;
  int w = threadIdx.x >> 6, lane = threadIdx.x & 63;
  int wr = w >> 1, wc = w & 1;
  int m0 = mt * 128 + wr * 64;
  int n0 = wc * 64;
  int lr = lane & 15, lg = lane >> 4;
  const u16* Wz = wt + z * 131072;
  f32x4 acc[4][4];
  for (int i = 0; i < 4; ++i) for (int j = 0; j < 4; ++j) acc[i][j] = (f32x4){0.f, 0.f, 0.f, 0.f};
  for (int k0 = 0; k0 < 1024; k0 += 32) {
    bf16x8 a[4], bfr[4];
    for (int i = 0; i < 4; ++i)
      a[i] = *(const bf16x8*)(xb + (long)(m0 + i * 16 + lr) * 1024 + k0 + lg * 8);
    for (int j = 0; j < 4; ++j)
      bfr[j] = *(const bf16x8*)(Wz + (long)(n0 + j * 16 + lr) * 1024 + k0 + lg * 8);
    for (int i = 0; i < 4; ++i)
      for (int j = 0; j < 4; ++j)
        acc[i][j] = __builtin_amdgcn_mfma_f32_16x16x32_bf16(a[i], bfr[j], acc[i][j], 0, 0, 0);
  }
  for (int i = 0; i < 4; ++i)
    for (int j = 0; j < 4; ++j)
      for (int r = 0; r < 4; ++r) {
        int m = m0 + i * 16 + lg * 4 + r;   // C layout: row=(lane>>4)*4+reg, col=lane&15
        int n = n0 + j * 16 + lr;
        u16 v = f2b(acc[i][j][r]);
        if (z == 0) qb[(long)m * 128 + n] = v;
        else if (z == 1) kb[(long)m * 128 + n] = v;
        else { int bb = m >> 12, sR = m & 4095; vt[(long)bb * 524288 + (long)n * 4096 + sR] = v; }
      }
}

// flash attention: 1 wave = 16 q rows, KVBLK=32, online softmax in log2 domain
__global__ __launch_bounds__(256) void k_attn(const u16* __restrict__ qb, const u16* __restrict__ kb,
                                              const u16* __restrict__ vt, const int* __restrict__ kmask,
                                              float* __restrict__ out) {
  const float SCALE_LOG2 = 0.08838834764831845f * 1.4426950408889634f;
  int qt = blockIdx.x, b = blockIdx.y;
  int w = threadIdx.x >> 6, lane = threadIdx.x & 63;
  int lr = lane & 15, lg = lane >> 4;
  int g = w * 64 + qt;        // work-balance interleave: block gets {qt,64+qt,128+qt,192+qt}
  int qrow0 = g * 16;
  const u16* Q = qb + ((long)(b * SQ + qrow0)) * HQ;
  const u16* K = kb + (long)b * SQ * HQ;
  const u16* V = vt + (long)b * HQ * SQ;   // V^T: [128][SQ]
  const int* msk = kmask + b * SQ;

  bf16x8 aq[4];
  for (int c = 0; c < 4; ++c) aq[c] = *(const bf16x8*)(Q + lr * HQ + c * 32 + lg * 8);

  f32x4 o[8];
  for (int n = 0; n < 8; ++n) o[n] = (f32x4){0.f, 0.f, 0.f, 0.f};
  float m_run[4], l_run[4];
  for (int r = 0; r < 4; ++r) { m_run[r] = -3e38f; l_run[r] = 0.f; }

  __shared__ __align__(16) u16 plds_all[4][16][40];  // per-wave P tile, padded rows (80B)

  int nkeys = qrow0 + 16;
  int nkt = (nkeys + 31) >> 5;
  for (int kt = 0; kt < nkt; ++kt) {
    int kb0 = kt * 32;
    f32x4 s[2];
    for (int h = 0; h < 2; ++h) {
      f32x4 acc = (f32x4){0.f, 0.f, 0.f, 0.f};
      const u16* Kp = K + (long)(kb0 + h * 16 + lr) * HQ + lg * 8;
      for (int c = 0; c < 4; ++c) {
        bf16x8 bk = *(const bf16x8*)(Kp + c * 32);
        acc = __builtin_amdgcn_mfma_f32_16x16x32_bf16(aq[c], bk, acc, 0, 0, 0);
      }
      s[h] = acc;
    }
    int mv0 = msk[kb0 + lr];
    int mv1 = msk[kb0 + 16 + lr];
    float ps[2][4];
    float alpha[4];
    for (int r = 0; r < 4; ++r) {
      int qr = qrow0 + lg * 4 + r;
      float s0 = ((kb0 + lr) <= qr && mv0 != 0) ? s[0][r] * SCALE_LOG2 : -3e38f;
      float s1 = ((kb0 + 16 + lr) <= qr && mv1 != 0) ? s[1][r] * SCALE_LOG2 : -3e38f;
      float t = fmaxf(s0, s1);
      t = fmaxf(t, __shfl_xor(t, 1));
      t = fmaxf(t, __shfl_xor(t, 2));
      t = fmaxf(t, __shfl_xor(t, 4));
      t = fmaxf(t, __shfl_xor(t, 8));
      float mnew = fmaxf(m_run[r], t);
      alpha[r] = __builtin_exp2f(m_run[r] - mnew);
      m_run[r] = mnew;
      float p0 = __builtin_exp2f(s0 - mnew);
      float p1 = __builtin_exp2f(s1 - mnew);
      ps[0][r] = p0; ps[1][r] = p1;
      float rs = p0 + p1;
      rs += __shfl_xor(rs, 1);
      rs += __shfl_xor(rs, 2);
      rs += __shfl_xor(rs, 4);
      rs += __shfl_xor(rs, 8);
      l_run[r] = l_run[r] * alpha[r] + rs;
    }
    for (int n = 0; n < 8; ++n)
      for (int r = 0; r < 4; ++r) o[n][r] *= alpha[r];
    // P (C-layout) -> LDS -> A-fragment layout
    for (int h = 0; h < 2; ++h)
      for (int r = 0; r < 4; ++r)
        plds_all[w][lg * 4 + r][h * 16 + lr] = f2b(ps[h][r]);
    bf16x8 ap = *(const bf16x8*)(&plds_all[w][lr][lg * 8]);  // intra-wave; lgkmcnt by compiler
    for (int n = 0; n < 8; ++n) {
      bf16x8 bv = *(const bf16x8*)(V + (long)(n * 16 + lr) * SQ + kb0 + lg * 8);
      o[n] = __builtin_amdgcn_mfma_f32_16x16x32_bf16(ap, bv, o[n], 0, 0, 0);
    }
  }
  for (int n = 0; n < 8; ++n)
    for (int r = 0; r < 4; ++r) {
      int qr = qrow0 + lg * 4 + r;
      out[((long)(b * SQ + qr)) * HQ + n * 16 + lr] = o[n][r] / l_run[r];
    }
}

extern "C" void kernel_launch(void* const* d_in, const int* in_sizes, int n_in,
                              void* d_out, int out_size, void* d_ws, size_t ws_size,
                              hipStream_t stream) {
  const float* x  = (const float*)d_in[0];
  const float* Wq = (const float*)d_in[1];
  const float* Wk = (const float*)d_in[2];
  const float* Wv = (const float*)d_in[3];
  const int* kmask = (const int*)d_in[4];
  char* ws = (char*)d_ws;
  u16* xb = (u16*)ws;                         // 32 MB: x as bf16
  u16* wt = (u16*)(ws + 33554432);            // 768 KB: Wt[3][128][1024]
  u16* qb = (u16*)(ws + 34340864);            // 4 MB: Q bf16 [16384][128]
  u16* kb = (u16*)(ws + 38535168);            // 4 MB: K bf16 [16384][128]
  u16* vt = (u16*)(ws + 42729472);            // 4 MB: V^T bf16 [4][128][4096]
  float* out = (float*)d_out;

  k_convx<<<8192, 256, 0, stream>>>(x, xb);
  k_wt<<<1536, 256, 0, stream>>>(Wq, Wk, Wv, wt);
  k_proj<<<dim3(128, 3), 256, 0, stream>>>(xb, wt, qb, kb, vt);
  k_attn<<<dim3(64, 4), 256, 0, stream>>>(qb, kb, vt, kmask, out);
}